// Round 2
// baseline (1923.193 us; speedup 1.0000x reference)
//
#include <hip/hip_runtime.h>
#include <math.h>

#define S_LEN 2048
#define BSZ   2
#define DM    1024
#define NH    16
#define DH    64
#define WIN   256

// ---------------------------------------------------------------------------
// GEMM: C = A @ W^T + bias.  A: M x K row-major (M=4096, K=1024),
// W: N x K row-major (N=1024).  BM=BN=128, BK=16, 256 threads, 8x8 microtile.
// MODE 0: scatter output to [b][h][s][dh] layout (+ optional q beta-scaling)
// MODE 1: plain row-major M x N output
// ---------------------------------------------------------------------------
template<int MODE, bool SCALE>
__global__ __launch_bounds__(256)
void gemm_nt(const float* __restrict__ A,
             const float* __restrict__ W,
             const float* __restrict__ bias,
             const float* __restrict__ beta,
             float* __restrict__ C)
{
    const int K = DM;
    __shared__ float As[16][128];
    __shared__ float Bs[16][128];

    const int tid   = threadIdx.x;
    const int rbase = blockIdx.x * 128;   // M block (32 blocks)
    const int nbase = blockIdx.y * 128;   // N block (8 blocks)
    const int lrow  = tid >> 1;           // 0..127
    const int lk    = (tid & 1) * 8;      // 0 or 8
    const int tm    = tid >> 4;           // 0..15
    const int tn    = tid & 15;           // 0..15

    const float* Ap = A + (size_t)(rbase + lrow) * K + lk;
    const float* Wp = W + (size_t)(nbase + lrow) * K + lk;

    float acc[8][8];
    #pragma unroll
    for (int i = 0; i < 8; ++i)
        #pragma unroll
        for (int j = 0; j < 8; ++j) acc[i][j] = 0.f;

    for (int ko = 0; ko < K; ko += 16) {
        float4 a0 = *(const float4*)(Ap + ko);
        float4 a1 = *(const float4*)(Ap + ko + 4);
        float4 b0 = *(const float4*)(Wp + ko);
        float4 b1 = *(const float4*)(Wp + ko + 4);
        __syncthreads();
        As[lk+0][lrow] = a0.x; As[lk+1][lrow] = a0.y;
        As[lk+2][lrow] = a0.z; As[lk+3][lrow] = a0.w;
        As[lk+4][lrow] = a1.x; As[lk+5][lrow] = a1.y;
        As[lk+6][lrow] = a1.z; As[lk+7][lrow] = a1.w;
        Bs[lk+0][lrow] = b0.x; Bs[lk+1][lrow] = b0.y;
        Bs[lk+2][lrow] = b0.z; Bs[lk+3][lrow] = b0.w;
        Bs[lk+4][lrow] = b1.x; Bs[lk+5][lrow] = b1.y;
        Bs[lk+6][lrow] = b1.z; Bs[lk+7][lrow] = b1.w;
        __syncthreads();
        #pragma unroll
        for (int kk = 0; kk < 16; ++kk) {
            float a[8], b[8];
            *(float4*)&a[0] = *(const float4*)&As[kk][tm*8];
            *(float4*)&a[4] = *(const float4*)&As[kk][tm*8 + 4];
            *(float4*)&b[0] = *(const float4*)&Bs[kk][tn*8];
            *(float4*)&b[4] = *(const float4*)&Bs[kk][tn*8 + 4];
            #pragma unroll
            for (int i = 0; i < 8; ++i)
                #pragma unroll
                for (int j = 0; j < 8; ++j)
                    acc[i][j] = fmaf(a[i], b[j], acc[i][j]);
        }
    }

    float bv[8];
    #pragma unroll
    for (int j = 0; j < 8; ++j) bv[j] = bias[nbase + tn*8 + j];

    if (MODE == 0) {
        // output col j = nbase + tn*8 + jj; head = j>>6 is constant per thread
        const int h  = (nbase + tn*8) >> 6;
        const int dh = (nbase + tn*8) & 63;
        float scl = 1.f;
        if (SCALE) scl = 0.125f * expf(-beta[h]);   // 1/(sqrt(64)*e^beta)
        #pragma unroll
        for (int i = 0; i < 8; ++i) {
            int r = rbase + tm*8 + i;
            int s = r >> 1, b = r & 1;
            float* op = C + (((size_t)(b*NH + h) * S_LEN + s) * DH + dh);
            float4 o0, o1;
            o0.x = (acc[i][0] + bv[0]) * scl;
            o0.y = (acc[i][1] + bv[1]) * scl;
            o0.z = (acc[i][2] + bv[2]) * scl;
            o0.w = (acc[i][3] + bv[3]) * scl;
            o1.x = (acc[i][4] + bv[4]) * scl;
            o1.y = (acc[i][5] + bv[5]) * scl;
            o1.z = (acc[i][6] + bv[6]) * scl;
            o1.w = (acc[i][7] + bv[7]) * scl;
            *(float4*)(op)     = o0;
            *(float4*)(op + 4) = o1;
        }
    } else {
        #pragma unroll
        for (int i = 0; i < 8; ++i) {
            int r = rbase + tm*8 + i;
            float* op = C + (size_t)r * DM + nbase + tn*8;
            float4 o0, o1;
            o0.x = acc[i][0] + bv[0];
            o0.y = acc[i][1] + bv[1];
            o0.z = acc[i][2] + bv[2];
            o0.w = acc[i][3] + bv[3];
            o1.x = acc[i][4] + bv[4];
            o1.y = acc[i][5] + bv[5];
            o1.z = acc[i][6] + bv[6];
            o1.w = acc[i][7] + bv[7];
            *(float4*)(op)     = o0;
            *(float4*)(op + 4) = o1;
        }
    }
}

// ---------------------------------------------------------------------------
// Dilated causal sliding-window attention, fp32, 1 thread = 1 query.
// Q/K/V in [b][h][s][dh]; output written as [s][b][h*64+dh] ( = (s,b,d) ).
// Keys for query s: t = s - 2j, j = 0..255, t >= 0. Online softmax.
// Score dot product uses 4 independent partial accumulators (chain = 16 FMA
// deep instead of 64) since occupancy here is only ~1 wave/SIMD.
// ---------------------------------------------------------------------------
__global__ __launch_bounds__(256)
void attn_kernel(const float* __restrict__ Q,
                 const float* __restrict__ K,
                 const float* __restrict__ V,
                 float* __restrict__ O)
{
    const int tid    = threadIdx.x;
    const int bh     = blockIdx.x >> 3;      // 0..31 (b*16+h)
    const int schunk = blockIdx.x & 7;
    const int s      = schunk * 256 + tid;   // 0..2047
    const int b      = bh >> 4;
    const int h      = bh & 15;

    const float4* qp = (const float4*)(Q + ((size_t)bh * S_LEN + s) * DH);
    float4 q[16];
    #pragma unroll
    for (int i = 0; i < 16; ++i) q[i] = qp[i];

    float4 o[16];
    #pragma unroll
    for (int i = 0; i < 16; ++i) o[i] = make_float4(0.f, 0.f, 0.f, 0.f);
    float m = -3.0e38f, l = 0.f;

    const float4* Kb = (const float4*)(K + (size_t)bh * S_LEN * DH);
    const float4* Vb = (const float4*)(V + (size_t)bh * S_LEN * DH);

    for (int j = 0; j < WIN; ++j) {
        int t = s - 2*j;
        if (t < 0) break;
        const float4* kr = Kb + (size_t)t * 16;
        float s0 = 0.f, s1 = 0.f, s2 = 0.f, s3 = 0.f;
        #pragma unroll
        for (int i = 0; i < 16; i += 4) {
            float4 k0 = kr[i], k1 = kr[i+1], k2 = kr[i+2], k3 = kr[i+3];
            s0 = fmaf(q[i].x,   k0.x, s0); s0 = fmaf(q[i].y,   k0.y, s0);
            s0 = fmaf(q[i].z,   k0.z, s0); s0 = fmaf(q[i].w,   k0.w, s0);
            s1 = fmaf(q[i+1].x, k1.x, s1); s1 = fmaf(q[i+1].y, k1.y, s1);
            s1 = fmaf(q[i+1].z, k1.z, s1); s1 = fmaf(q[i+1].w, k1.w, s1);
            s2 = fmaf(q[i+2].x, k2.x, s2); s2 = fmaf(q[i+2].y, k2.y, s2);
            s2 = fmaf(q[i+2].z, k2.z, s2); s2 = fmaf(q[i+2].w, k2.w, s2);
            s3 = fmaf(q[i+3].x, k3.x, s3); s3 = fmaf(q[i+3].y, k3.y, s3);
            s3 = fmaf(q[i+3].z, k3.z, s3); s3 = fmaf(q[i+3].w, k3.w, s3);
        }
        float sc = (s0 + s1) + (s2 + s3);
        // branchless online softmax update
        float mn = fmaxf(m, sc);
        float f  = __expf(m - mn);     // first iter: exp(-huge) = 0
        float w  = __expf(sc - mn);
        l = l * f + w;
        m = mn;
        const float4* vr = Vb + (size_t)t * 16;
        #pragma unroll
        for (int i = 0; i < 16; ++i) {
            float4 vv = vr[i];
            o[i].x = fmaf(w, vv.x, o[i].x * f);
            o[i].y = fmaf(w, vv.y, o[i].y * f);
            o[i].z = fmaf(w, vv.z, o[i].z * f);
            o[i].w = fmaf(w, vv.w, o[i].w * f);
        }
    }

    const float inv = 1.f / l;
    float* op = O + ((size_t)s * BSZ + b) * DM + h * DH;
    #pragma unroll
    for (int i = 0; i < 16; ++i) {
        float4 ov;
        ov.x = o[i].x * inv; ov.y = o[i].y * inv;
        ov.z = o[i].z * inv; ov.w = o[i].w * inv;
        ((float4*)op)[i] = ov;
    }
}

// ---------------------------------------------------------------------------
extern "C" void kernel_launch(void* const* d_in, const int* in_sizes, int n_in,
                              void* d_out, int out_size, void* d_ws, size_t ws_size,
                              hipStream_t stream)
{
    const float* x    = (const float*)d_in[0];
    const float* q_w  = (const float*)d_in[1];
    const float* q_b  = (const float*)d_in[2];
    const float* k_w  = (const float*)d_in[3];
    const float* k_b  = (const float*)d_in[4];
    const float* v_w  = (const float*)d_in[5];
    const float* v_b  = (const float*)d_in[6];
    const float* o_w  = (const float*)d_in[7];
    const float* o_b  = (const float*)d_in[8];
    const float* beta = (const float*)d_in[9];
    float* out = (float*)d_out;

    const size_t TSZ = (size_t)BSZ * NH * S_LEN * DH;  // 4,194,304 floats
    float* qws = (float*)d_ws;
    float* kws = qws + TSZ;
    float* vws = kws + TSZ;
    float* aws = vws + TSZ;   // attention output in (s,b,d) layout

    dim3 gg(32, 8), bb(256);
    gemm_nt<0, true ><<<gg, bb, 0, stream>>>(x, q_w, q_b, beta, qws);
    gemm_nt<0, false><<<gg, bb, 0, stream>>>(x, k_w, k_b, nullptr, kws);
    gemm_nt<0, false><<<gg, bb, 0, stream>>>(x, v_w, v_b, nullptr, vws);
    attn_kernel<<<dim3(256), dim3(256), 0, stream>>>(qws, kws, vws, aws);
    gemm_nt<1, false><<<gg, bb, 0, stream>>>(aws, o_w, o_b, nullptr, out);
}

// Round 3
// 756.865 us; speedup vs baseline: 2.5410x; 2.5410x over previous
//
#include <hip/hip_runtime.h>
#include <math.h>

#define S_LEN 2048
#define BSZ   2
#define DM    1024
#define NH    16
#define DH    64
#define WIN   256
#define U_LEN 1024   // S_LEN / 2 (per-parity sub-sequence length)

// ---------------------------------------------------------------------------
// GEMM: C = A @ W^T + bias.  A: M x K row-major (M=4096, K=1024),
// W: N x K row-major (N=1024).  BM=BN=128, BK=16, 256 threads, 8x8 microtile.
// MODE 0: scatter output to [b][h][p][u][dh] parity-split layout
//         (+ optional q beta-scaling).  p = s&1, u = s>>1, s = row>>1.
// MODE 1: plain row-major M x N output
// ---------------------------------------------------------------------------
template<int MODE, bool SCALE>
__global__ __launch_bounds__(256)
void gemm_nt(const float* __restrict__ A,
             const float* __restrict__ W,
             const float* __restrict__ bias,
             const float* __restrict__ beta,
             float* __restrict__ C)
{
    const int K = DM;
    __shared__ float As[16][128];
    __shared__ float Bs[16][128];

    const int tid   = threadIdx.x;
    const int rbase = blockIdx.x * 128;   // M block (32 blocks)
    const int nbase = blockIdx.y * 128;   // N block (8 blocks)
    const int lrow  = tid >> 1;           // 0..127
    const int lk    = (tid & 1) * 8;      // 0 or 8
    const int tm    = tid >> 4;           // 0..15
    const int tn    = tid & 15;           // 0..15

    const float* Ap = A + (size_t)(rbase + lrow) * K + lk;
    const float* Wp = W + (size_t)(nbase + lrow) * K + lk;

    float acc[8][8];
    #pragma unroll
    for (int i = 0; i < 8; ++i)
        #pragma unroll
        for (int j = 0; j < 8; ++j) acc[i][j] = 0.f;

    for (int ko = 0; ko < K; ko += 16) {
        float4 a0 = *(const float4*)(Ap + ko);
        float4 a1 = *(const float4*)(Ap + ko + 4);
        float4 b0 = *(const float4*)(Wp + ko);
        float4 b1 = *(const float4*)(Wp + ko + 4);
        __syncthreads();
        As[lk+0][lrow] = a0.x; As[lk+1][lrow] = a0.y;
        As[lk+2][lrow] = a0.z; As[lk+3][lrow] = a0.w;
        As[lk+4][lrow] = a1.x; As[lk+5][lrow] = a1.y;
        As[lk+6][lrow] = a1.z; As[lk+7][lrow] = a1.w;
        Bs[lk+0][lrow] = b0.x; Bs[lk+1][lrow] = b0.y;
        Bs[lk+2][lrow] = b0.z; Bs[lk+3][lrow] = b0.w;
        Bs[lk+4][lrow] = b1.x; Bs[lk+5][lrow] = b1.y;
        Bs[lk+6][lrow] = b1.z; Bs[lk+7][lrow] = b1.w;
        __syncthreads();
        #pragma unroll
        for (int kk = 0; kk < 16; ++kk) {
            float a[8], b[8];
            *(float4*)&a[0] = *(const float4*)&As[kk][tm*8];
            *(float4*)&a[4] = *(const float4*)&As[kk][tm*8 + 4];
            *(float4*)&b[0] = *(const float4*)&Bs[kk][tn*8];
            *(float4*)&b[4] = *(const float4*)&Bs[kk][tn*8 + 4];
            #pragma unroll
            for (int i = 0; i < 8; ++i)
                #pragma unroll
                for (int j = 0; j < 8; ++j)
                    acc[i][j] = fmaf(a[i], b[j], acc[i][j]);
        }
    }

    float bv[8];
    #pragma unroll
    for (int j = 0; j < 8; ++j) bv[j] = bias[nbase + tn*8 + j];

    if (MODE == 0) {
        // output col j = nbase + tn*8 + jj; head h = col>>6 constant per thread
        const int h  = (nbase + tn*8) >> 6;
        const int dh = (nbase + tn*8) & 63;
        float scl = 1.f;
        if (SCALE) scl = 0.125f * expf(-beta[h]);   // 1/(sqrt(64)*e^beta)
        #pragma unroll
        for (int i = 0; i < 8; ++i) {
            int r = rbase + tm*8 + i;
            int b = r & 1;           // batch
            int p = (r >> 1) & 1;    // parity of s
            int u = r >> 2;          // s >> 1
            float* op = C + ((((size_t)(b*NH + h)*2 + p) * U_LEN + u) * DH + dh);
            float4 o0, o1;
            o0.x = (acc[i][0] + bv[0]) * scl;
            o0.y = (acc[i][1] + bv[1]) * scl;
            o0.z = (acc[i][2] + bv[2]) * scl;
            o0.w = (acc[i][3] + bv[3]) * scl;
            o1.x = (acc[i][4] + bv[4]) * scl;
            o1.y = (acc[i][5] + bv[5]) * scl;
            o1.z = (acc[i][6] + bv[6]) * scl;
            o1.w = (acc[i][7] + bv[7]) * scl;
            *(float4*)(op)     = o0;
            *(float4*)(op + 4) = o1;
        }
    } else {
        #pragma unroll
        for (int i = 0; i < 8; ++i) {
            int r = rbase + tm*8 + i;
            float* op = C + (size_t)r * DM + nbase + tn*8;
            float4 o0, o1;
            o0.x = acc[i][0] + bv[0];
            o0.y = acc[i][1] + bv[1];
            o0.z = acc[i][2] + bv[2];
            o0.w = acc[i][3] + bv[3];
            o1.x = acc[i][4] + bv[4];
            o1.y = acc[i][5] + bv[5];
            o1.z = acc[i][6] + bv[6];
            o1.w = acc[i][7] + bv[7];
            *(float4*)(op)     = o0;
            *(float4*)(op + 4) = o1;
        }
    }
}

// ---------------------------------------------------------------------------
// Parity-split sliding-window attention, fp32.
// In u-space the dilated window is a standard causal window of 256 keys:
//   query u attends keys u' in [max(0, u-255), u].
// Q/K/V layout: [b][h][p][u][64].  Output written to (s, b, d) row-major
// for the final O-projection GEMM: row = s*BSZ + b, col = h*64 + dh.
//
// Block: 128 threads. Each thread: 2 adjacent queries x 16 dims.
//   c  = tid & 3   -> dim group (16 dims)
//   qi = tid >> 2  -> query pair; u0 = U0 + 2*qi, u1 = u0 + 1
// K/V staged in LDS in 64-row chunks. Score reduced across the 4 dim-group
// lanes with __shfl_xor (quad_perm DPP).  Per-thread loop bounds skip
// out-of-window keys; only one boundary predicate per query remains.
// ---------------------------------------------------------------------------
__global__ __launch_bounds__(128)
void attn_kernel(const float* __restrict__ Q,
                 const float* __restrict__ K,
                 const float* __restrict__ V,
                 float* __restrict__ O)
{
    __shared__ float Ks[64][64];
    __shared__ float Vs[64][64];

    const int tid = threadIdx.x;
    const int U0  = blockIdx.x * 64;     // query tile base (16 tiles)
    const int bhp = blockIdx.y;          // 0..63 = ((b*16 + h)*2 + p)
    const int p   = bhp & 1;
    const int h   = (bhp >> 1) & 15;
    const int b   = bhp >> 5;

    const int c  = tid & 3;              // dim group
    const int qi = tid >> 2;             // 0..31
    const int u0 = U0 + 2*qi;
    const int u1 = u0 + 1;

    const float* Qb = Q + (size_t)bhp * U_LEN * DH;
    const float* Kb = K + (size_t)bhp * U_LEN * DH;
    const float* Vb = V + (size_t)bhp * U_LEN * DH;

    // load the two query fragments (16 dims each)
    float q0r[16], q1r[16];
    {
        const float4* q0p = (const float4*)(Qb + (size_t)u0 * DH + c*16);
        const float4* q1p = (const float4*)(Qb + (size_t)u1 * DH + c*16);
        #pragma unroll
        for (int i = 0; i < 4; ++i) {
            *(float4*)&q0r[i*4] = q0p[i];
            *(float4*)&q1r[i*4] = q1p[i];
        }
    }

    float o0[16], o1[16];
    #pragma unroll
    for (int i = 0; i < 16; ++i) { o0[i] = 0.f; o1[i] = 0.f; }
    float m0 = -3.0e38f, l0 = 0.f;
    float m1 = -3.0e38f, l1 = 0.f;

    const int Cs = (U0 > 255 ? (U0 - 255) : 0) & ~63;   // first chunk (64-aligned)
    const int lo0 = (u0 > 255) ? (u0 - 255) : 0;        // window lower bound, q0
    const int lo1 = (u1 > 255) ? (u1 - 255) : 0;        // window lower bound, q1

    for (int C = Cs; C <= U0 + 63; C += 64) {
        // ---- stage K/V chunk: rows C..C+63 (always in [0, 1023]) ----
        __syncthreads();
        {
            const float4* Ksrc = (const float4*)(Kb + (size_t)C * DH);
            const float4* Vsrc = (const float4*)(Vb + (size_t)C * DH);
            float4* Kdst = (float4*)&Ks[0][0];
            float4* Vdst = (float4*)&Vs[0][0];
            #pragma unroll
            for (int i = 0; i < 8; ++i) {
                int f = tid + i*128;          // 1024 float4s per array
                Kdst[f] = Ksrc[f];
                Vdst[f] = Vsrc[f];
            }
        }
        __syncthreads();

        // ---- per-thread key loop over this chunk ----
        const int lo = (C   > lo0) ? C   : lo0;
        const int hi = (C + 63 < u1) ? C + 63 : u1;
        for (int tp = lo; tp <= hi; ++tp) {
            const int r = tp - C;
            float kk[16], vv[16];
            #pragma unroll
            for (int i = 0; i < 4; ++i) {
                *(float4*)&kk[i*4] = *(const float4*)&Ks[r][c*16 + i*4];
                *(float4*)&vv[i*4] = *(const float4*)&Vs[r][c*16 + i*4];
            }
            // partial dots (2 accumulators each for ILP)
            float d0a = 0.f, d0b = 0.f, d1a = 0.f, d1b = 0.f;
            #pragma unroll
            for (int i = 0; i < 8; ++i) {
                d0a = fmaf(q0r[i],   kk[i],   d0a);
                d0b = fmaf(q0r[i+8], kk[i+8], d0b);
                d1a = fmaf(q1r[i],   kk[i],   d1a);
                d1b = fmaf(q1r[i+8], kk[i+8], d1b);
            }
            float s0 = d0a + d0b;
            float s1 = d1a + d1b;
            // reduce across the 4 dim-group lanes (quad)
            s0 += __shfl_xor(s0, 1, 64); s0 += __shfl_xor(s0, 2, 64);
            s1 += __shfl_xor(s1, 1, 64); s1 += __shfl_xor(s1, 2, 64);

            // online softmax updates (masked at the single open boundary)
            const bool v0 = (tp <= u0);     // causal bound for q0
            const bool v1 = (tp >= lo1);    // window lower bound for q1
            float mn0 = v0 ? fmaxf(m0, s0) : m0;
            float mn1 = v1 ? fmaxf(m1, s1) : m1;
            float w0  = v0 ? __expf(s0 - mn0) : 0.f;
            float w1  = v1 ? __expf(s1 - mn1) : 0.f;
            float f0  = __expf(m0 - mn0);
            float f1  = __expf(m1 - mn1);
            l0 = l0 * f0 + w0;  m0 = mn0;
            l1 = l1 * f1 + w1;  m1 = mn1;

            #pragma unroll
            for (int i = 0; i < 16; ++i) {
                o0[i] = fmaf(w0, vv[i], o0[i] * f0);
                o1[i] = fmaf(w1, vv[i], o1[i] * f1);
            }
        }
    }

    // ---- epilogue: O[(2u+p)*BSZ + b][h*64 + c*16 .. +16) = o / l ----
    const float inv0 = 1.f / l0;
    const float inv1 = 1.f / l1;
    float* op0 = O + ((size_t)((2*u0 + p) * BSZ + b)) * DM + h*DH + c*16;
    float* op1 = O + ((size_t)((2*u1 + p) * BSZ + b)) * DM + h*DH + c*16;
    #pragma unroll
    for (int i = 0; i < 4; ++i) {
        float4 w0, w1;
        w0.x = o0[i*4+0]*inv0; w0.y = o0[i*4+1]*inv0;
        w0.z = o0[i*4+2]*inv0; w0.w = o0[i*4+3]*inv0;
        w1.x = o1[i*4+0]*inv1; w1.y = o1[i*4+1]*inv1;
        w1.z = o1[i*4+2]*inv1; w1.w = o1[i*4+3]*inv1;
        ((float4*)op0)[i] = w0;
        ((float4*)op1)[i] = w1;
    }
}

// ---------------------------------------------------------------------------
extern "C" void kernel_launch(void* const* d_in, const int* in_sizes, int n_in,
                              void* d_out, int out_size, void* d_ws, size_t ws_size,
                              hipStream_t stream)
{
    const float* x    = (const float*)d_in[0];
    const float* q_w  = (const float*)d_in[1];
    const float* q_b  = (const float*)d_in[2];
    const float* k_w  = (const float*)d_in[3];
    const float* k_b  = (const float*)d_in[4];
    const float* v_w  = (const float*)d_in[5];
    const float* v_b  = (const float*)d_in[6];
    const float* o_w  = (const float*)d_in[7];
    const float* o_b  = (const float*)d_in[8];
    const float* beta = (const float*)d_in[9];
    float* out = (float*)d_out;

    const size_t TSZ = (size_t)BSZ * NH * S_LEN * DH;  // 4,194,304 floats
    float* qws = (float*)d_ws;
    float* kws = qws + TSZ;
    float* vws = kws + TSZ;
    float* aws = vws + TSZ;   // attention output in (s,b,d) layout

    dim3 gg(32, 8), bb(256);
    gemm_nt<0, true ><<<gg, bb, 0, stream>>>(x, q_w, q_b, beta, qws);
    gemm_nt<0, false><<<gg, bb, 0, stream>>>(x, k_w, k_b, nullptr, kws);
    gemm_nt<0, false><<<gg, bb, 0, stream>>>(x, v_w, v_b, nullptr, vws);
    attn_kernel<<<dim3(16, 64), dim3(128), 0, stream>>>(qws, kws, vws, aws);
    gemm_nt<1, false><<<gg, bb, 0, stream>>>(aws, o_w, o_b, nullptr, out);
}

// Round 4
// 343.656 us; speedup vs baseline: 5.5963x; 2.2024x over previous
//
#include <hip/hip_runtime.h>
#include <math.h>

#define S_LEN 2048
#define BSZ   2
#define DM    1024
#define NH    16
#define DH    64
#define WIN   256
#define U_LEN 1024   // S_LEN / 2 (per-parity sub-sequence length)

typedef __attribute__((ext_vector_type(4))) float          f32x4;
typedef __attribute__((ext_vector_type(8))) short          bf16x8;
typedef __attribute__((ext_vector_type(8))) unsigned short u16x8;

// RNE float -> bf16 (values are normal floats here; NaN path not needed)
__device__ __forceinline__ unsigned short f2bf(float x) {
    unsigned u = __float_as_uint(x);
    u += 0x7fffu + ((u >> 16) & 1u);
    return (unsigned short)(u >> 16);
}
__device__ __forceinline__ float bf2f(unsigned short h) {
    return __uint_as_float(((unsigned)h) << 16);
}

__device__ __forceinline__ void load_lds16(const void* g, void* l) {
    __builtin_amdgcn_global_load_lds(
        (const __attribute__((address_space(1))) unsigned int*)g,
        (__attribute__((address_space(3))) unsigned int*)l, 16, 0, 0);
}

// ---------------------------------------------------------------------------
// split fp32 -> (hi, lo) bf16 pair.  8 floats / thread, vectorized.
// ---------------------------------------------------------------------------
__global__ __launch_bounds__(256)
void split_bf16(const float* __restrict__ in,
                unsigned short* __restrict__ hi,
                unsigned short* __restrict__ lo, int n8)
{
    int idx = blockIdx.x * 256 + threadIdx.x;
    if (idx >= n8) return;
    const float4* ip = (const float4*)(in + (size_t)idx * 8);
    float4 v0 = ip[0], v1 = ip[1];
    float v[8] = {v0.x, v0.y, v0.z, v0.w, v1.x, v1.y, v1.z, v1.w};
    unsigned short h[8], l[8];
    #pragma unroll
    for (int i = 0; i < 8; ++i) {
        h[i] = f2bf(v[i]);
        l[i] = f2bf(v[i] - bf2f(h[i]));
    }
    *(u16x8*)(hi + (size_t)idx * 8) = *(const u16x8*)h;
    *(u16x8*)(lo + (size_t)idx * 8) = *(const u16x8*)l;
}

// ---------------------------------------------------------------------------
// Split-bf16 MFMA GEMM:  C = A @ W^T + bias,  A: 4096 x 1024 (hi/lo bf16),
// W: 1024 x 1024 (hi/lo bf16), fp32 accumulate via 3 MFMA products
// (hi*hi + hi*lo + lo*hi).  BM=64, BN=128, BK=64, 256 threads = 4 waves
// (2m x 2n), per-wave 32x64 = 2x4 fragments of 16x16x32.
// LDS tiles have 128B rows, XOR-swizzled (kb ^= (row&7)<<4) applied on the
// pre-swizzled GLOBAL source for global_load_lds + on the ds_read address
// (both-sides rule).  2-barrier K-loop, 12 x global_load_lds(16B) per step.
// MODE 0: scatter to parity layout [b][h][p][u][dh] (+ optional beta scale)
// MODE 1: plain row-major M x N fp32 output
// ---------------------------------------------------------------------------
template<int MODE, bool SCALE>
__global__ __launch_bounds__(256, 2)
void gemm_mfma(const unsigned short* __restrict__ Ahi,
               const unsigned short* __restrict__ Alo,
               const unsigned short* __restrict__ Whi,
               const unsigned short* __restrict__ Wlo,
               const float* __restrict__ bias,
               const float* __restrict__ beta,
               float* __restrict__ C)
{
    __shared__ char lds[49152];
    char* As_hi = lds;              //  64 rows x 128B
    char* As_lo = lds + 8*1024;
    char* Bs_hi = lds + 16*1024;    // 128 rows x 128B
    char* Bs_lo = lds + 32*1024;

    const int tid   = threadIdx.x;
    const int lane  = tid & 63;
    const int wid   = tid >> 6;
    const int wr    = wid & 1;           // m half (32 rows)
    const int wc    = wid >> 1;          // n half (64 cols)
    const int rbase = blockIdx.x * 64;
    const int nbase = blockIdx.y * 128;

    f32x4 acc[2][4] = {};

    // staging descriptors: linear LDS byte L=(i*256+tid)*16 -> row r=L>>7,
    // in-row byte x=L&127; global element = (x ^ ((r&7)<<4))/2
    int a_r[2], a_e[2];
    #pragma unroll
    for (int i = 0; i < 2; ++i) {
        int L = (i*256 + tid) * 16;
        int r = L >> 7, x = L & 127;
        a_r[i] = r; a_e[i] = (x ^ ((r & 7) << 4)) >> 1;
    }
    int b_r[4], b_e[4];
    #pragma unroll
    for (int i = 0; i < 4; ++i) {
        int L = (i*256 + tid) * 16;
        int r = L >> 7, x = L & 127;
        b_r[i] = r; b_e[i] = (x ^ ((r & 7) << 4)) >> 1;
    }

    for (int ko = 0; ko < DM; ko += 64) {
        __syncthreads();   // previous compute done before overwrite
        #pragma unroll
        for (int i = 0; i < 2; ++i) {
            size_t ge = (size_t)(rbase + a_r[i]) * DM + ko + a_e[i];
            int    lo = (i*256 + tid) * 16;
            load_lds16(Ahi + ge, As_hi + lo);
            load_lds16(Alo + ge, As_lo + lo);
        }
        #pragma unroll
        for (int i = 0; i < 4; ++i) {
            size_t ge = (size_t)(nbase + b_r[i]) * DM + ko + b_e[i];
            int    lo = (i*256 + tid) * 16;
            load_lds16(Whi + ge, Bs_hi + lo);
            load_lds16(Wlo + ge, Bs_lo + lo);
        }
        __syncthreads();   // vmcnt drained by compiler before barrier

        #pragma unroll
        for (int ks = 0; ks < 2; ++ks) {
            bf16x8 ah[2], al[2], bh[4], bl[4];
            #pragma unroll
            for (int mf = 0; mf < 2; ++mf) {
                int r  = wr*32 + mf*16 + (lane & 15);
                int kb = ((ks*64) + ((lane >> 4) << 4)) ^ ((r & 7) << 4);
                ah[mf] = *(const bf16x8*)(As_hi + r*128 + kb);
                al[mf] = *(const bf16x8*)(As_lo + r*128 + kb);
            }
            #pragma unroll
            for (int nf = 0; nf < 4; ++nf) {
                int r  = wc*64 + nf*16 + (lane & 15);
                int kb = ((ks*64) + ((lane >> 4) << 4)) ^ ((r & 7) << 4);
                bh[nf] = *(const bf16x8*)(Bs_hi + r*128 + kb);
                bl[nf] = *(const bf16x8*)(Bs_lo + r*128 + kb);
            }
            #pragma unroll
            for (int mf = 0; mf < 2; ++mf)
                #pragma unroll
                for (int nf = 0; nf < 4; ++nf) {
                    acc[mf][nf] = __builtin_amdgcn_mfma_f32_16x16x32_bf16(ah[mf], bh[nf], acc[mf][nf], 0, 0, 0);
                    acc[mf][nf] = __builtin_amdgcn_mfma_f32_16x16x32_bf16(ah[mf], bl[nf], acc[mf][nf], 0, 0, 0);
                    acc[mf][nf] = __builtin_amdgcn_mfma_f32_16x16x32_bf16(al[mf], bh[nf], acc[mf][nf], 0, 0, 0);
                }
        }
    }

    // epilogue: C/D layout col = lane&15, row = (lane>>4)*4 + j  [m89-verified]
    const int colq = nbase + wc*64 + (lane & 15);
    const int rowq = rbase + wr*32 + ((lane >> 4) << 2);
    #pragma unroll
    for (int nf = 0; nf < 4; ++nf) {
        const int col = colq + nf*16;
        const float bv = bias[col];
        if (MODE == 0) {
            const int h  = col >> 6;
            const int dh = col & 63;
            float scl = 1.f;
            if (SCALE) scl = 0.125f * __expf(-beta[h]);   // 1/(sqrt(64)*e^beta)
            #pragma unroll
            for (int mf = 0; mf < 2; ++mf)
                #pragma unroll
                for (int j = 0; j < 4; ++j) {
                    int r = rowq + mf*16 + j;
                    int b = r & 1, p = (r >> 1) & 1, u = r >> 2;
                    C[(((size_t)((b*NH + h)*2 + p)) * U_LEN + u) * DH + dh] =
                        (acc[mf][nf][j] + bv) * scl;
                }
        } else {
            #pragma unroll
            for (int mf = 0; mf < 2; ++mf)
                #pragma unroll
                for (int j = 0; j < 4; ++j) {
                    int r = rowq + mf*16 + j;
                    C[(size_t)r * DM + col] = acc[mf][nf][j] + bv;
                }
        }
    }
}

// ---------------------------------------------------------------------------
// Parity-split sliding-window attention, fp32 compute (unchanged from R3),
// epilogue now emits (hi, lo) bf16 pair for the split-bf16 O-projection.
// ---------------------------------------------------------------------------
__global__ __launch_bounds__(128)
void attn_kernel(const float* __restrict__ Q,
                 const float* __restrict__ K,
                 const float* __restrict__ V,
                 unsigned short* __restrict__ Ohi,
                 unsigned short* __restrict__ Olo)
{
    __shared__ float Ks[64][64];
    __shared__ float Vs[64][64];

    const int tid = threadIdx.x;
    const int U0  = blockIdx.x * 64;
    const int bhp = blockIdx.y;          // ((b*16 + h)*2 + p)
    const int p   = bhp & 1;
    const int h   = (bhp >> 1) & 15;
    const int b   = bhp >> 5;

    const int c  = tid & 3;
    const int qi = tid >> 2;
    const int u0 = U0 + 2*qi;
    const int u1 = u0 + 1;

    const float* Qb = Q + (size_t)bhp * U_LEN * DH;
    const float* Kb = K + (size_t)bhp * U_LEN * DH;
    const float* Vb = V + (size_t)bhp * U_LEN * DH;

    float q0r[16], q1r[16];
    {
        const float4* q0p = (const float4*)(Qb + (size_t)u0 * DH + c*16);
        const float4* q1p = (const float4*)(Qb + (size_t)u1 * DH + c*16);
        #pragma unroll
        for (int i = 0; i < 4; ++i) {
            *(float4*)&q0r[i*4] = q0p[i];
            *(float4*)&q1r[i*4] = q1p[i];
        }
    }

    float o0[16], o1[16];
    #pragma unroll
    for (int i = 0; i < 16; ++i) { o0[i] = 0.f; o1[i] = 0.f; }
    float m0 = -3.0e38f, l0 = 0.f;
    float m1 = -3.0e38f, l1 = 0.f;

    const int Cs  = (U0 > 255 ? (U0 - 255) : 0) & ~63;
    const int lo0 = (u0 > 255) ? (u0 - 255) : 0;
    const int lo1 = (u1 > 255) ? (u1 - 255) : 0;

    for (int C = Cs; C <= U0 + 63; C += 64) {
        __syncthreads();
        {
            const float4* Ksrc = (const float4*)(Kb + (size_t)C * DH);
            const float4* Vsrc = (const float4*)(Vb + (size_t)C * DH);
            float4* Kdst = (float4*)&Ks[0][0];
            float4* Vdst = (float4*)&Vs[0][0];
            #pragma unroll
            for (int i = 0; i < 8; ++i) {
                int f = tid + i*128;
                Kdst[f] = Ksrc[f];
                Vdst[f] = Vsrc[f];
            }
        }
        __syncthreads();

        const int lo = (C      > lo0) ? C      : lo0;
        const int hi = (C + 63 < u1 ) ? C + 63 : u1;
        for (int tp = lo; tp <= hi; ++tp) {
            const int r = tp - C;
            float kk[16], vv[16];
            #pragma unroll
            for (int i = 0; i < 4; ++i) {
                *(float4*)&kk[i*4] = *(const float4*)&Ks[r][c*16 + i*4];
                *(float4*)&vv[i*4] = *(const float4*)&Vs[r][c*16 + i*4];
            }
            float d0a = 0.f, d0b = 0.f, d1a = 0.f, d1b = 0.f;
            #pragma unroll
            for (int i = 0; i < 8; ++i) {
                d0a = fmaf(q0r[i],   kk[i],   d0a);
                d0b = fmaf(q0r[i+8], kk[i+8], d0b);
                d1a = fmaf(q1r[i],   kk[i],   d1a);
                d1b = fmaf(q1r[i+8], kk[i+8], d1b);
            }
            float s0 = d0a + d0b;
            float s1 = d1a + d1b;
            s0 += __shfl_xor(s0, 1, 64); s0 += __shfl_xor(s0, 2, 64);
            s1 += __shfl_xor(s1, 1, 64); s1 += __shfl_xor(s1, 2, 64);

            const bool v0 = (tp <= u0);
            const bool v1 = (tp >= lo1);
            float mn0 = v0 ? fmaxf(m0, s0) : m0;
            float mn1 = v1 ? fmaxf(m1, s1) : m1;
            float w0  = v0 ? __expf(s0 - mn0) : 0.f;
            float w1  = v1 ? __expf(s1 - mn1) : 0.f;
            float f0  = __expf(m0 - mn0);
            float f1  = __expf(m1 - mn1);
            l0 = l0 * f0 + w0;  m0 = mn0;
            l1 = l1 * f1 + w1;  m1 = mn1;

            #pragma unroll
            for (int i = 0; i < 16; ++i) {
                o0[i] = fmaf(w0, vv[i], o0[i] * f0);
                o1[i] = fmaf(w1, vv[i], o1[i] * f1);
            }
        }
    }

    const float inv0 = 1.f / l0;
    const float inv1 = 1.f / l1;
    const size_t r0 = (size_t)((2*u0 + p) * BSZ + b) * DM + h*DH + c*16;
    const size_t r1 = (size_t)((2*u1 + p) * BSZ + b) * DM + h*DH + c*16;
    unsigned short h0[16], l0a[16], h1[16], l1a[16];
    #pragma unroll
    for (int i = 0; i < 16; ++i) {
        float a = o0[i] * inv0;
        float bq = o1[i] * inv1;
        h0[i]  = f2bf(a);  l0a[i] = f2bf(a  - bf2f(h0[i]));
        h1[i]  = f2bf(bq); l1a[i] = f2bf(bq - bf2f(h1[i]));
    }
    *(u16x8*)(Ohi + r0)     = *(const u16x8*)&h0[0];
    *(u16x8*)(Ohi + r0 + 8) = *(const u16x8*)&h0[8];
    *(u16x8*)(Olo + r0)     = *(const u16x8*)&l0a[0];
    *(u16x8*)(Olo + r0 + 8) = *(const u16x8*)&l0a[8];
    *(u16x8*)(Ohi + r1)     = *(const u16x8*)&h1[0];
    *(u16x8*)(Ohi + r1 + 8) = *(const u16x8*)&h1[8];
    *(u16x8*)(Olo + r1)     = *(const u16x8*)&l1a[0];
    *(u16x8*)(Olo + r1 + 8) = *(const u16x8*)&l1a[8];
}

// ---------------------------------------------------------------------------
extern "C" void kernel_launch(void* const* d_in, const int* in_sizes, int n_in,
                              void* d_out, int out_size, void* d_ws, size_t ws_size,
                              hipStream_t stream)
{
    const float* x    = (const float*)d_in[0];
    const float* q_w  = (const float*)d_in[1];
    const float* q_b  = (const float*)d_in[2];
    const float* k_w  = (const float*)d_in[3];
    const float* k_b  = (const float*)d_in[4];
    const float* v_w  = (const float*)d_in[5];
    const float* v_b  = (const float*)d_in[6];
    const float* o_w  = (const float*)d_in[7];
    const float* o_b  = (const float*)d_in[8];
    const float* beta = (const float*)d_in[9];
    float* out = (float*)d_out;

    const size_t TSZ = (size_t)BSZ * NH * S_LEN * DH;   // 4,194,304
    const size_t WSZ = (size_t)DM * DM;                 // 1,048,576

    // workspace layout (62.9 MB total; d_out doubles as Q scratch):
    float*          kws  = (float*)d_ws;                //  fp32 K  (16.8 MB)
    float*          vws  = kws + TSZ;                   //  fp32 V  (16.8 MB)
    unsigned short* x_hi = (unsigned short*)(vws + TSZ);//  bf16    ( 8.4 MB)
    unsigned short* x_lo = x_hi + TSZ;                  //  bf16    ( 8.4 MB)
    unsigned short* qwh  = x_lo + TSZ;                  //  weights (12.6 MB)
    unsigned short* qwl  = qwh + WSZ;
    unsigned short* kwh  = qwl + WSZ;
    unsigned short* kwl  = kwh + WSZ;
    unsigned short* vwh  = kwl + WSZ;
    unsigned short* vwl  = vwh + WSZ;
    float*          qws  = out;                         //  Q scratch = d_out
    unsigned short* awh  = x_hi;                        //  attn out hi (reuse)
    unsigned short* awl  = x_lo;                        //  attn out lo (reuse)
    unsigned short* owh  = qwh;                         //  o_w hi (reuse)
    unsigned short* owl  = qwl;                         //  o_w lo (reuse)

    // 1) fp32 -> hi/lo bf16 splits
    split_bf16<<<dim3(2048), dim3(256), 0, stream>>>(x,   x_hi, x_lo, (int)(TSZ/8));
    split_bf16<<<dim3(512),  dim3(256), 0, stream>>>(q_w, qwh,  qwl,  (int)(WSZ/8));
    split_bf16<<<dim3(512),  dim3(256), 0, stream>>>(k_w, kwh,  kwl,  (int)(WSZ/8));
    split_bf16<<<dim3(512),  dim3(256), 0, stream>>>(v_w, vwh,  vwl,  (int)(WSZ/8));

    // 2) Q/K/V projections (MFMA, parity-scatter epilogue)
    dim3 gg(64, 8), bb(256);
    gemm_mfma<0, true ><<<gg, bb, 0, stream>>>(x_hi, x_lo, qwh, qwl, q_b, beta, qws);
    gemm_mfma<0, false><<<gg, bb, 0, stream>>>(x_hi, x_lo, kwh, kwl, k_b, nullptr, kws);
    gemm_mfma<0, false><<<gg, bb, 0, stream>>>(x_hi, x_lo, vwh, vwl, v_b, nullptr, vws);

    // 3) attention (fp32), writes hi/lo bf16 into recycled x_hi/x_lo space
    attn_kernel<<<dim3(16, 64), dim3(128), 0, stream>>>(qws, kws, vws, awh, awl);

    // 4) O-projection (o_w split recycles the q_w slot)
    split_bf16<<<dim3(512), dim3(256), 0, stream>>>(o_w, owh, owl, (int)(WSZ/8));
    gemm_mfma<1, false><<<gg, bb, 0, stream>>>(awh, awl, owh, owl, o_b, nullptr, out);
}

// Round 5
// 246.035 us; speedup vs baseline: 7.8167x; 1.3968x over previous
//
#include <hip/hip_runtime.h>
#include <math.h>

#define S_LEN 2048
#define BSZ   2
#define DM    1024
#define NH    16
#define DH    64
#define WIN   256
#define U_LEN 1024   // S_LEN / 2 (per-parity sub-sequence length)
#define NEGF  -3.0e38f

typedef __attribute__((ext_vector_type(4))) float          f32x4;
typedef __attribute__((ext_vector_type(8))) short          bf16x8;
typedef __attribute__((ext_vector_type(8))) unsigned short u16x8;

// RNE float -> bf16 (used by the standalone split kernel)
__device__ __forceinline__ unsigned short f2bf(float x) {
    unsigned u = __float_as_uint(x);
    u += 0x7fffu + ((u >> 16) & 1u);
    return (unsigned short)(u >> 16);
}
__device__ __forceinline__ float bf2f(unsigned short h) {
    return __uint_as_float(((unsigned)h) << 16);
}

__device__ __forceinline__ void load_lds16(const void* g, void* l) {
    __builtin_amdgcn_global_load_lds(
        (const __attribute__((address_space(1))) unsigned int*)g,
        (__attribute__((address_space(3))) unsigned int*)l, 16, 0, 0);
}

// truncation split: v = bf2f(hi) + ~bf2f(lo), error ~2^-16 relative
__device__ __forceinline__ void splitT(float v, unsigned short& hi, unsigned short& lo) {
    unsigned u = __float_as_uint(v);
    hi = (unsigned short)(u >> 16);
    float r = v - __uint_as_float(u & 0xffff0000u);
    lo = (unsigned short)(__float_as_uint(r) >> 16);
}

// ---------------------------------------------------------------------------
// split fp32 -> (hi, lo) bf16 pair.  8 floats / thread, vectorized.
// ---------------------------------------------------------------------------
__global__ __launch_bounds__(256)
void split_bf16(const float* __restrict__ in,
                unsigned short* __restrict__ hi,
                unsigned short* __restrict__ lo, int n8)
{
    int idx = blockIdx.x * 256 + threadIdx.x;
    if (idx >= n8) return;
    const float4* ip = (const float4*)(in + (size_t)idx * 8);
    float4 v0 = ip[0], v1 = ip[1];
    float v[8] = {v0.x, v0.y, v0.z, v0.w, v1.x, v1.y, v1.z, v1.w};
    unsigned short h[8], l[8];
    #pragma unroll
    for (int i = 0; i < 8; ++i) {
        h[i] = f2bf(v[i]);
        l[i] = f2bf(v[i] - bf2f(h[i]));
    }
    *(u16x8*)(hi + (size_t)idx * 8) = *(const u16x8*)h;
    *(u16x8*)(lo + (size_t)idx * 8) = *(const u16x8*)l;
}

// ---------------------------------------------------------------------------
// Split-bf16 MFMA GEMM (unchanged from R4):  C = A @ W^T + bias.
// BM=64, BN=128, BK=64, 256 threads = 4 waves, 3-product hi/lo accumulate.
// MODE 0: scatter to parity layout [b][h][p][u][dh] (+ optional beta scale)
// MODE 1: plain row-major M x N fp32 output
// ---------------------------------------------------------------------------
template<int MODE, bool SCALE>
__global__ __launch_bounds__(256, 2)
void gemm_mfma(const unsigned short* __restrict__ Ahi,
               const unsigned short* __restrict__ Alo,
               const unsigned short* __restrict__ Whi,
               const unsigned short* __restrict__ Wlo,
               const float* __restrict__ bias,
               const float* __restrict__ beta,
               float* __restrict__ C)
{
    __shared__ char lds[49152];
    char* As_hi = lds;              //  64 rows x 128B
    char* As_lo = lds + 8*1024;
    char* Bs_hi = lds + 16*1024;    // 128 rows x 128B
    char* Bs_lo = lds + 32*1024;

    const int tid   = threadIdx.x;
    const int lane  = tid & 63;
    const int wid   = tid >> 6;
    const int wr    = wid & 1;
    const int wc    = wid >> 1;
    const int rbase = blockIdx.x * 64;
    const int nbase = blockIdx.y * 128;

    f32x4 acc[2][4] = {};

    int a_r[2], a_e[2];
    #pragma unroll
    for (int i = 0; i < 2; ++i) {
        int L = (i*256 + tid) * 16;
        int r = L >> 7, x = L & 127;
        a_r[i] = r; a_e[i] = (x ^ ((r & 7) << 4)) >> 1;
    }
    int b_r[4], b_e[4];
    #pragma unroll
    for (int i = 0; i < 4; ++i) {
        int L = (i*256 + tid) * 16;
        int r = L >> 7, x = L & 127;
        b_r[i] = r; b_e[i] = (x ^ ((r & 7) << 4)) >> 1;
    }

    for (int ko = 0; ko < DM; ko += 64) {
        __syncthreads();
        #pragma unroll
        for (int i = 0; i < 2; ++i) {
            size_t ge = (size_t)(rbase + a_r[i]) * DM + ko + a_e[i];
            int    lo = (i*256 + tid) * 16;
            load_lds16(Ahi + ge, As_hi + lo);
            load_lds16(Alo + ge, As_lo + lo);
        }
        #pragma unroll
        for (int i = 0; i < 4; ++i) {
            size_t ge = (size_t)(nbase + b_r[i]) * DM + ko + b_e[i];
            int    lo = (i*256 + tid) * 16;
            load_lds16(Whi + ge, Bs_hi + lo);
            load_lds16(Wlo + ge, Bs_lo + lo);
        }
        __syncthreads();

        #pragma unroll
        for (int ks = 0; ks < 2; ++ks) {
            bf16x8 ah[2], al[2], bh[4], bl[4];
            #pragma unroll
            for (int mf = 0; mf < 2; ++mf) {
                int r  = wr*32 + mf*16 + (lane & 15);
                int kb = ((ks*64) + ((lane >> 4) << 4)) ^ ((r & 7) << 4);
                ah[mf] = *(const bf16x8*)(As_hi + r*128 + kb);
                al[mf] = *(const bf16x8*)(As_lo + r*128 + kb);
            }
            #pragma unroll
            for (int nf = 0; nf < 4; ++nf) {
                int r  = wc*64 + nf*16 + (lane & 15);
                int kb = ((ks*64) + ((lane >> 4) << 4)) ^ ((r & 7) << 4);
                bh[nf] = *(const bf16x8*)(Bs_hi + r*128 + kb);
                bl[nf] = *(const bf16x8*)(Bs_lo + r*128 + kb);
            }
            #pragma unroll
            for (int mf = 0; mf < 2; ++mf)
                #pragma unroll
                for (int nf = 0; nf < 4; ++nf) {
                    acc[mf][nf] = __builtin_amdgcn_mfma_f32_16x16x32_bf16(ah[mf], bh[nf], acc[mf][nf], 0, 0, 0);
                    acc[mf][nf] = __builtin_amdgcn_mfma_f32_16x16x32_bf16(ah[mf], bl[nf], acc[mf][nf], 0, 0, 0);
                    acc[mf][nf] = __builtin_amdgcn_mfma_f32_16x16x32_bf16(al[mf], bh[nf], acc[mf][nf], 0, 0, 0);
                }
        }
    }

    const int colq = nbase + wc*64 + (lane & 15);
    const int rowq = rbase + wr*32 + ((lane >> 4) << 2);
    #pragma unroll
    for (int nf = 0; nf < 4; ++nf) {
        const int col = colq + nf*16;
        const float bv = bias[col];
        if (MODE == 0) {
            const int h  = col >> 6;
            const int dh = col & 63;
            float scl = 1.f;
            if (SCALE) scl = 0.125f * __expf(-beta[h]);
            #pragma unroll
            for (int mf = 0; mf < 2; ++mf)
                #pragma unroll
                for (int j = 0; j < 4; ++j) {
                    int r = rowq + mf*16 + j;
                    int b = r & 1, p = (r >> 1) & 1, u = r >> 2;
                    C[(((size_t)((b*NH + h)*2 + p)) * U_LEN + u) * DH + dh] =
                        (acc[mf][nf][j] + bv) * scl;
                }
        } else {
            #pragma unroll
            for (int mf = 0; mf < 2; ++mf)
                #pragma unroll
                for (int j = 0; j < 4; ++j) {
                    int r = rowq + mf*16 + j;
                    C[(size_t)r * DM + col] = acc[mf][nf][j] + bv;
                }
        }
    }
}

// ---------------------------------------------------------------------------
// MFMA flash attention in u-space, full split-bf16 precision.
// Per block: 4 waves x 16 queries (QBLK=64), K/V tiles of 64 keys.
// Swapped QK^T (S^T = K.Q^T) with permuted K rows so the P fragment is
// lane-local for PV (O^T = V^T.P^T).  K LDS [64 key][64 d], V^T LDS
// [64 dv][64 key], both bf16 hi/lo with 128B rows, XOR-swizzled
// (byte ^= (row&7)<<4) on both write and read.
// ---------------------------------------------------------------------------
__global__ __launch_bounds__(256)
void attn_mfma(const float* __restrict__ Q,
               const float* __restrict__ K,
               const float* __restrict__ V,
               unsigned short* __restrict__ Ohi,
               unsigned short* __restrict__ Olo)
{
    __shared__ char lds[32768];
    char* KhL = lds;                // K hi: 64 rows x 128B
    char* KlL = lds + 8192;         // K lo
    char* ThL = lds + 16384;        // V^T hi: 64 dv-rows x 128B (64 keys x 2B)
    char* TlL = lds + 24576;        // V^T lo

    const int tid  = threadIdx.x;
    const int lane = tid & 63;
    const int w    = tid >> 6;           // wave 0..3
    const int U0   = blockIdx.x * 64;    // query tile base
    const int bhp  = blockIdx.y;         // ((b*16 + h)*2 + p)
    const int p    = bhp & 1;
    const int h    = (bhp >> 1) & 15;
    const int b    = bhp >> 5;

    const int lq = lane & 15;            // query index within wave tile
    const int lg = lane >> 4;            // lane group 0..3
    const int U0w = U0 + w*16;
    const int qu  = U0w + lq;            // this lane's query u

    const float* Qb = Q + (size_t)bhp * U_LEN * DH;
    const float* Kb = K + (size_t)bhp * U_LEN * DH;
    const float* Vb = V + (size_t)bhp * U_LEN * DH;

    // ---- Q fragments (B-operand: col=q, k-elems d = lg*8.. / 32+lg*8..) ----
    bf16x8 qh0, ql0, qh1, ql1;
    {
        const float* qp = Qb + (size_t)qu * DH + lg*8;
        float v0[8], v1[8];
        *(float4*)&v0[0] = *(const float4*)(qp);
        *(float4*)&v0[4] = *(const float4*)(qp + 4);
        *(float4*)&v1[0] = *(const float4*)(qp + 32);
        *(float4*)&v1[4] = *(const float4*)(qp + 36);
        u16x8 h0, l0, h1, l1;
        #pragma unroll
        for (int i = 0; i < 8; ++i) {
            unsigned short a, c;
            splitT(v0[i], a, c); h0[i] = a; l0[i] = c;
            splitT(v1[i], a, c); h1[i] = a; l1[i] = c;
        }
        qh0 = *(bf16x8*)&h0; ql0 = *(bf16x8*)&l0;
        qh1 = *(bf16x8*)&h1; ql1 = *(bf16x8*)&l1;
    }

    f32x4 acc[4] = {};                   // O^T: 4 dv-tiles of 16
    float m = NEGF, lsum = 0.f;

    const int wave_lo = (U0w > 255) ? (U0w - 255) : 0;
    const int wave_hi = U0w + 15;
    const int C0 = ((U0 > 255) ? (U0 - 255) : 0) & ~63;

    for (int C = C0; C <= U0 + 63; C += 64) {
        __syncthreads();   // previous tile's LDS reads complete
        // ---- stage K (bf16 split, row-major) ----
        #pragma unroll
        for (int ci = 0; ci < 2; ++ci) {
            int c   = tid + ci*256;
            int row = c >> 3;
            int dc  = (c & 7) * 8;
            const float* src = Kb + (size_t)(C + row) * DH + dc;
            float4 f0 = *(const float4*)src;
            float4 f1 = *(const float4*)(src + 4);
            float v[8] = {f0.x, f0.y, f0.z, f0.w, f1.x, f1.y, f1.z, f1.w};
            u16x8 hh, ll;
            #pragma unroll
            for (int i = 0; i < 8; ++i) {
                unsigned short a, c2;
                splitT(v[i], a, c2); hh[i] = a; ll[i] = c2;
            }
            int ba = row*128 + ((dc*2) ^ ((row & 7) << 4));
            *(u16x8*)(KhL + ba) = hh;
            *(u16x8*)(KlL + ba) = ll;
        }
        // ---- stage V transposed (bf16 split): Vt[dv][key] ----
        {
            int rp = tid >> 3;           // key pair 0..31
            int dc = (tid & 7) * 8;
            const float* s0 = Vb + (size_t)(C + 2*rp) * DH + dc;
            const float* s1 = s0 + DH;
            float4 a0 = *(const float4*)s0, a1 = *(const float4*)(s0 + 4);
            float4 b0 = *(const float4*)s1, b1 = *(const float4*)(s1 + 4);
            float va[8] = {a0.x, a0.y, a0.z, a0.w, a1.x, a1.y, a1.z, a1.w};
            float vb[8] = {b0.x, b0.y, b0.z, b0.w, b1.x, b1.y, b1.z, b1.w};
            #pragma unroll
            for (int i = 0; i < 8; ++i) {
                int dv = dc + i;
                unsigned ua = __float_as_uint(va[i]);
                unsigned ub = __float_as_uint(vb[i]);
                unsigned hp = (ua >> 16) | (ub & 0xffff0000u);
                float ra = va[i] - __uint_as_float(ua & 0xffff0000u);
                float rb = vb[i] - __uint_as_float(ub & 0xffff0000u);
                unsigned lp = (__float_as_uint(ra) >> 16) | (__float_as_uint(rb) & 0xffff0000u);
                int ba = dv*128 + ((rp*4) ^ ((dv & 7) << 4));
                *(unsigned*)(ThL + ba) = hp;
                *(unsigned*)(TlL + ba) = lp;
            }
        }
        __syncthreads();

        if (C + 63 >= wave_lo && C <= wave_hi) {
            // ---- QK^T: 4 S-tiles (swapped, permuted K rows) ----
            f32x4 S[4];
            #pragma unroll
            for (int T = 0; T < 4; ++T) {
                int prow = ((lq >> 2)*8 + (lq & 3)) + (T & 1)*4 + (T >> 1)*32;
                int sw = (prow & 7) << 4;
                int b0 = prow*128 + ((lg*16) ^ sw);
                int b1 = prow*128 + ((64 + lg*16) ^ sw);
                bf16x8 kh0 = *(const bf16x8*)(KhL + b0);
                bf16x8 kl0 = *(const bf16x8*)(KlL + b0);
                bf16x8 kh1 = *(const bf16x8*)(KhL + b1);
                bf16x8 kl1 = *(const bf16x8*)(KlL + b1);
                f32x4 s = {};
                s = __builtin_amdgcn_mfma_f32_16x16x32_bf16(kh0, qh0, s, 0, 0, 0);
                s = __builtin_amdgcn_mfma_f32_16x16x32_bf16(kh0, ql0, s, 0, 0, 0);
                s = __builtin_amdgcn_mfma_f32_16x16x32_bf16(kl0, qh0, s, 0, 0, 0);
                s = __builtin_amdgcn_mfma_f32_16x16x32_bf16(kh1, qh1, s, 0, 0, 0);
                s = __builtin_amdgcn_mfma_f32_16x16x32_bf16(kh1, ql1, s, 0, 0, 0);
                s = __builtin_amdgcn_mfma_f32_16x16x32_bf16(kl1, qh1, s, 0, 0, 0);
                S[T] = s;
            }
            // ---- masked online softmax (lane's key j of tile T = C + lg*8 +
            //      (T&1)*4 + (T>>1)*32 + j; all-invalid tiles self-correct) ----
            float e[16];
            #pragma unroll
            for (int T = 0; T < 4; ++T)
                #pragma unroll
                for (int j = 0; j < 4; ++j) {
                    int key = C + lg*8 + (T & 1)*4 + (T >> 1)*32 + j;
                    float x = S[T][j];
                    e[T*4 + j] = (key <= qu && key >= qu - 255) ? x : NEGF;
                }
            float mx = e[0];
            #pragma unroll
            for (int i = 1; i < 16; ++i) mx = fmaxf(mx, e[i]);
            mx = fmaxf(mx, __shfl_xor(mx, 16, 64));
            mx = fmaxf(mx, __shfl_xor(mx, 32, 64));
            float mn = fmaxf(m, mx);
            float f  = __expf(m - mn);
            float ws = 0.f;
            #pragma unroll
            for (int i = 0; i < 16; ++i) { e[i] = __expf(e[i] - mn); ws += e[i]; }
            ws += __shfl_xor(ws, 16, 64);
            ws += __shfl_xor(ws, 32, 64);
            lsum = lsum * f + ws;
            m = mn;
            #pragma unroll
            for (int nf = 0; nf < 4; ++nf)
                #pragma unroll
                for (int j = 0; j < 4; ++j) acc[nf][j] *= f;
            // ---- pack P hi/lo (lane-local; element i of half H = key lg*8+i (+32H)) ----
            u16x8 p0h, p0l, p1h, p1l;
            #pragma unroll
            for (int i = 0; i < 8; ++i) {
                unsigned short a, c2;
                splitT(e[i],     a, c2); p0h[i] = a; p0l[i] = c2;
                splitT(e[i + 8], a, c2); p1h[i] = a; p1l[i] = c2;
            }
            bf16x8 ph0 = *(bf16x8*)&p0h, pl0 = *(bf16x8*)&p0l;
            bf16x8 ph1 = *(bf16x8*)&p1h, pl1 = *(bf16x8*)&p1l;
            // ---- PV: O^T += V^T . P^T ----
            #pragma unroll
            for (int nf = 0; nf < 4; ++nf) {
                int dvr = nf*16 + lq;
                int sw = (dvr & 7) << 4;
                int b0 = dvr*128 + ((lg*16) ^ sw);
                int b1 = dvr*128 + ((64 + lg*16) ^ sw);
                bf16x8 vh0 = *(const bf16x8*)(ThL + b0);
                bf16x8 vl0 = *(const bf16x8*)(TlL + b0);
                bf16x8 vh1 = *(const bf16x8*)(ThL + b1);
                bf16x8 vl1 = *(const bf16x8*)(TlL + b1);
                acc[nf] = __builtin_amdgcn_mfma_f32_16x16x32_bf16(vh0, ph0, acc[nf], 0, 0, 0);
                acc[nf] = __builtin_amdgcn_mfma_f32_16x16x32_bf16(vh0, pl0, acc[nf], 0, 0, 0);
                acc[nf] = __builtin_amdgcn_mfma_f32_16x16x32_bf16(vl0, ph0, acc[nf], 0, 0, 0);
                acc[nf] = __builtin_amdgcn_mfma_f32_16x16x32_bf16(vh1, ph1, acc[nf], 0, 0, 0);
                acc[nf] = __builtin_amdgcn_mfma_f32_16x16x32_bf16(vh1, pl1, acc[nf], 0, 0, 0);
                acc[nf] = __builtin_amdgcn_mfma_f32_16x16x32_bf16(vl1, ph1, acc[nf], 0, 0, 0);
            }
        }
    }

    // ---- epilogue: out row = (2u+p)*BSZ + b; lane owns dv = nf*16 + lg*4 + j ----
    const float inv = 1.f / lsum;
    const int srow = (2*qu + p) * BSZ + b;
    unsigned short* oh = Ohi + (size_t)srow * DM + h*DH;
    unsigned short* ol = Olo + (size_t)srow * DM + h*DH;
    #pragma unroll
    for (int nf = 0; nf < 4; ++nf) {
        ushort4 hh, ll;
        unsigned short a, c2;
        splitT(acc[nf][0] * inv, a, c2); hh.x = a; ll.x = c2;
        splitT(acc[nf][1] * inv, a, c2); hh.y = a; ll.y = c2;
        splitT(acc[nf][2] * inv, a, c2); hh.z = a; ll.z = c2;
        splitT(acc[nf][3] * inv, a, c2); hh.w = a; ll.w = c2;
        *(ushort4*)(oh + nf*16 + lg*4) = hh;
        *(ushort4*)(ol + nf*16 + lg*4) = ll;
    }
}

// ---------------------------------------------------------------------------
extern "C" void kernel_launch(void* const* d_in, const int* in_sizes, int n_in,
                              void* d_out, int out_size, void* d_ws, size_t ws_size,
                              hipStream_t stream)
{
    const float* x    = (const float*)d_in[0];
    const float* q_w  = (const float*)d_in[1];
    const float* q_b  = (const float*)d_in[2];
    const float* k_w  = (const float*)d_in[3];
    const float* k_b  = (const float*)d_in[4];
    const float* v_w  = (const float*)d_in[5];
    const float* v_b  = (const float*)d_in[6];
    const float* o_w  = (const float*)d_in[7];
    const float* o_b  = (const float*)d_in[8];
    const float* beta = (const float*)d_in[9];
    float* out = (float*)d_out;

    const size_t TSZ = (size_t)BSZ * NH * S_LEN * DH;   // 4,194,304
    const size_t WSZ = (size_t)DM * DM;                 // 1,048,576

    float*          kws  = (float*)d_ws;                //  fp32 K  (16.8 MB)
    float*          vws  = kws + TSZ;                   //  fp32 V  (16.8 MB)
    unsigned short* x_hi = (unsigned short*)(vws + TSZ);//  bf16    ( 8.4 MB)
    unsigned short* x_lo = x_hi + TSZ;                  //  bf16    ( 8.4 MB)
    unsigned short* qwh  = x_lo + TSZ;                  //  weights (12.6 MB)
    unsigned short* qwl  = qwh + WSZ;
    unsigned short* kwh  = qwl + WSZ;
    unsigned short* kwl  = kwh + WSZ;
    unsigned short* vwh  = kwl + WSZ;
    unsigned short* vwl  = vwh + WSZ;
    float*          qws  = out;                         //  Q scratch = d_out
    unsigned short* awh  = x_hi;                        //  attn out hi (reuse)
    unsigned short* awl  = x_lo;                        //  attn out lo (reuse)
    unsigned short* owh  = qwh;                         //  o_w hi (reuse)
    unsigned short* owl  = qwl;                         //  o_w lo (reuse)

    // 1) fp32 -> hi/lo bf16 splits
    split_bf16<<<dim3(2048), dim3(256), 0, stream>>>(x,   x_hi, x_lo, (int)(TSZ/8));
    split_bf16<<<dim3(512),  dim3(256), 0, stream>>>(q_w, qwh,  qwl,  (int)(WSZ/8));
    split_bf16<<<dim3(512),  dim3(256), 0, stream>>>(k_w, kwh,  kwl,  (int)(WSZ/8));
    split_bf16<<<dim3(512),  dim3(256), 0, stream>>>(v_w, vwh,  vwl,  (int)(WSZ/8));

    // 2) Q/K/V projections (MFMA, parity-scatter epilogue)
    dim3 gg(64, 8), bb(256);
    gemm_mfma<0, true ><<<gg, bb, 0, stream>>>(x_hi, x_lo, qwh, qwl, q_b, beta, qws);
    gemm_mfma<0, false><<<gg, bb, 0, stream>>>(x_hi, x_lo, kwh, kwl, k_b, nullptr, kws);
    gemm_mfma<0, false><<<gg, bb, 0, stream>>>(x_hi, x_lo, vwh, vwl, v_b, nullptr, vws);

    // 3) MFMA flash attention, writes hi/lo bf16 into recycled x_hi/x_lo
    attn_mfma<<<dim3(16, 64), dim3(256), 0, stream>>>(qws, kws, vws, awh, awl);

    // 4) O-projection (o_w split recycles the q_w slot)
    split_bf16<<<dim3(512), dim3(256), 0, stream>>>(o_w, owh, owl, (int)(WSZ/8));
    gemm_mfma<1, false><<<gg, bb, 0, stream>>>(awh, awl, owh, owl, o_b, nullptr, out);
}